// Round 4
// baseline (307.436 us; speedup 1.0000x reference)
//
#include <hip/hip_runtime.h>
#include <hip/hip_fp16.h>

typedef _Float16 f16;
typedef _Float16 f16x4 __attribute__((ext_vector_type(4)));
typedef _Float16 f16x8 __attribute__((ext_vector_type(8)));
typedef float f32x4 __attribute__((ext_vector_type(4)));

constexpr int C = 128;     // channels
constexpr int V = 65536;   // voxels
constexpr int VPB = 32;    // voxels per block (fused kernel)
constexpr int PTS = 64;    // points per MFMA tile
constexpr int BLOCK = 256; // 4 waves

union U16 { uint4 u; f16x8 h; };

// -------------------------------------------------------------------------
// CSR build: histogram -> exclusive scan -> scatter ids
// -------------------------------------------------------------------------
__global__ void hist_kernel(const int* __restrict__ idx, int* __restrict__ cnt, int n) {
    int t = blockIdx.x * blockDim.x + threadIdx.x;
    if (t < n) atomicAdd(&cnt[idx[t]], 1);
}

__global__ void scan_block(const int* __restrict__ cnt, int* __restrict__ off,
                           int* __restrict__ bsum) {
    __shared__ int s[256];
    const int i = blockIdx.x * 256 + threadIdx.x;
    const int x = cnt[i];
    s[threadIdx.x] = x;
    __syncthreads();
    for (int d = 1; d < 256; d <<= 1) {
        int y = (threadIdx.x >= d) ? s[threadIdx.x - d] : 0;
        __syncthreads();
        s[threadIdx.x] += y;
        __syncthreads();
    }
    off[i] = s[threadIdx.x] - x;  // exclusive
    if (threadIdx.x == 255) bsum[blockIdx.x] = s[255];
}

__global__ void scan_bsum(int* __restrict__ bsum) {
    __shared__ int s[256];
    const int x = bsum[threadIdx.x];
    s[threadIdx.x] = x;
    __syncthreads();
    for (int d = 1; d < 256; d <<= 1) {
        int y = (threadIdx.x >= d) ? s[threadIdx.x - d] : 0;
        __syncthreads();
        s[threadIdx.x] += y;
        __syncthreads();
    }
    bsum[threadIdx.x] = s[threadIdx.x] - x;
}

__global__ void add_bsum(int* __restrict__ off, const int* __restrict__ bsum) {
    off[blockIdx.x * 256 + threadIdx.x] += bsum[blockIdx.x];
}

// After this kernel, off[v] = INCLUSIVE prefix end for voxel v.
__global__ void scatter_ids(const int* __restrict__ idx, int* __restrict__ off,
                            int* __restrict__ csr, int n) {
    int t = blockIdx.x * blockDim.x + threadIdx.x;
    if (t < n) {
        const int v = idx[t];
        const int slot = atomicAdd(&off[v], 1);
        csr[slot] = t;
    }
}

// -------------------------------------------------------------------------
// Fused pooling + 2-layer MLP, one block per 32 consecutive voxels.
// Phase A: per-voxel fp32 mean -> f16 means in LDS.
// Phase B: per 64-point tile: os/f staged f16 swizzled, MFMA layer1,
//          h round-trip, MFMA layer2, scatter-store fp32 out rows.
// -------------------------------------------------------------------------
__global__ void __launch_bounds__(BLOCK, 2)
fused_pool_mlp(const float* __restrict__ feats,
               const float* __restrict__ W1g, const float* __restrict__ b1g,
               const float* __restrict__ W2g, const float* __restrict__ b2g,
               const int* __restrict__ csr, const int* __restrict__ off,
               float* __restrict__ out) {
    __shared__ f16 os_lds[PTS * C];     // 16 KB, XOR-swizzled rows
    __shared__ f16 f_lds[PTS * C];      // 16 KB
    __shared__ f16 h_lds[PTS * C];      // 16 KB
    __shared__ f16 means[VPB * C];      // 8 KB (f16 voxel means)
    __shared__ int ends_lds[VPB];       // inclusive CSR ends per local voxel
    __shared__ int s0_sh;
    __shared__ int pmap[PTS];           // point id per tile slot

    const int t = threadIdx.x;
    const int lane = t & 63;
    const int wv = t >> 6;
    const int l15 = lane & 15;
    const int lg = lane >> 4;
    const int chBase = 32 * wv;
    const int v0 = blockIdx.x * VPB;

    if (t < VPB) ends_lds[t] = off[v0 + t];
    if (t == 0) s0_sh = (v0 == 0) ? 0 : off[v0 - 1];

    // ---- Weight fragments in registers (B-frag: col=lane&15, k=(lane>>4)*8+j)
    const int ch0 = chBase + l15;
    const int ch1 = chBase + 16 + l15;
    f16x8 w1f[2][4], w2f[2][4];
#pragma unroll
    for (int m = 0; m < 2; ++m) {
        const int ch = (m == 0) ? ch0 : ch1;
#pragma unroll
        for (int s = 0; s < 4; ++s) {
            f16x8 a, b;
#pragma unroll
            for (int j = 0; j < 8; ++j) {
                const int k = s * 32 + lg * 8 + j;
                a[j] = (f16)W1g[k * C + ch];
                b[j] = (f16)W2g[k * C + ch];
            }
            w1f[m][s] = a;
            w2f[m][s] = b;
        }
    }
    const float b1v[2] = {b1g[ch0], b1g[ch1]};
    const float b2v[2] = {b2g[ch0], b2g[ch1]};

    // ---- Phase A: voxel means (half-wave per voxel, 4 voxels each) -------
    {
        const int half = lane >> 5;
        const int l32 = lane & 31;
        const int ch = l32 * 4;
#pragma unroll
        for (int i = 0; i < VPB / 8; ++i) {
            const int vl = (wv * 2 + half) * (VPB / 8) + i;
            const int v = v0 + vl;
            const int s = (v == 0) ? 0 : off[v - 1];
            const int e = off[v];
            f32x4 a0 = {0.f, 0.f, 0.f, 0.f};
            f32x4 a1 = {0.f, 0.f, 0.f, 0.f};
            int j = s;
            for (; j + 2 <= e; j += 2) {
                const int p0 = csr[j];
                const int p1 = csr[j + 1];
                a0 += *reinterpret_cast<const f32x4*>(feats + (size_t)p0 * C + ch);
                a1 += *reinterpret_cast<const f32x4*>(feats + (size_t)p1 * C + ch);
            }
            if (j < e) {
                const int p0 = csr[j];
                a0 += *reinterpret_cast<const f32x4*>(feats + (size_t)p0 * C + ch);
            }
            a0 += a1;
            const float rc = (e > s) ? 1.0f / (float)(e - s) : 0.f;
            f16x4 mv;
            mv[0] = (f16)(a0[0] * rc);
            mv[1] = (f16)(a0[1] * rc);
            mv[2] = (f16)(a0[2] * rc);
            mv[3] = (f16)(a0[3] * rc);
            *reinterpret_cast<f16x4*>(means + vl * C + ch) = mv;
        }
    }
    __syncthreads();  // means + ends ready

    const int s0 = s0_sh;
    const int eTot = ends_lds[VPB - 1];
    const int npts = eTot - s0;

    const int sp = t >> 2;
    const int sc = (t & 3) * 32;

    for (int tile = 0; tile * PTS < npts; ++tile) {
        const int tbase = s0 + tile * PTS;
        // ---- Stage os (= f - mean) and f into LDS as f16, swizzled ------
        {
            const int slot = tbase + sp;
            const bool valid = slot < eTot;
            int p = 0;
            union { uint4 u[8]; float f[32]; f32x4 v[8]; } ff;
            union { uint4 u[4]; f16 h[32]; } mm;
            if (valid) {
                p = csr[slot];
                // local voxel id: count of inclusive-ends <= slot
                int vloc = 0;
#pragma unroll
                for (int i = 0; i < VPB - 1; ++i) vloc += (slot >= ends_lds[i]);
#pragma unroll
                for (int j = 0; j < 8; ++j)
                    ff.v[j] = *reinterpret_cast<const f32x4*>(feats + (size_t)p * C + sc + j * 4);
                const uint4* mp = reinterpret_cast<const uint4*>(means + vloc * C + sc);
#pragma unroll
                for (int j = 0; j < 4; ++j) mm.u[j] = mp[j];
            } else {
#pragma unroll
                for (int j = 0; j < 8; ++j) ff.u[j] = make_uint4(0, 0, 0, 0);
#pragma unroll
                for (int j = 0; j < 4; ++j) mm.u[j] = make_uint4(0, 0, 0, 0);
            }
            if ((t & 3) == 0) pmap[sp] = p;
            union { uint4 u[4]; f16 h[32]; } osv, fvh;
#pragma unroll
            for (int j = 0; j < 32; ++j) {
                const float fj = ff.f[j];
                const float mj = (float)mm.h[j];
                osv.h[j] = (f16)(fj - mj);
                fvh.h[j] = (f16)fj;
            }
#pragma unroll
            for (int u = 0; u < 4; ++u) {
                const int byte = (sp * 256 + (sc + u * 8) * 2) ^ ((sp & 7) << 4);
                *reinterpret_cast<uint4*>(reinterpret_cast<char*>(os_lds) + byte) = osv.u[u];
                *reinterpret_cast<uint4*>(reinterpret_cast<char*>(f_lds) + byte) = fvh.u[u];
            }
        }
        __syncthreads();

        // ---- Layer 1: acc = os @ W1 + b1 ---------------------------------
        f32x4 acc[2][4];
#pragma unroll
        for (int m = 0; m < 2; ++m)
#pragma unroll
            for (int q = 0; q < 4; ++q)
                acc[m][q] = (f32x4){b1v[m], b1v[m], b1v[m], b1v[m]};

#pragma unroll
        for (int s = 0; s < 4; ++s) {
            f16x8 af[4];
#pragma unroll
            for (int q = 0; q < 4; ++q) {
                const int p = q * 16 + l15;
                const int byte = (p * 256 + (s * 32 + lg * 8) * 2) ^ ((p & 7) << 4);
                U16 tmp;
                tmp.u = *reinterpret_cast<const uint4*>(reinterpret_cast<const char*>(os_lds) + byte);
                af[q] = tmp.h;
            }
#pragma unroll
            for (int m = 0; m < 2; ++m)
#pragma unroll
                for (int q = 0; q < 4; ++q)
                    acc[m][q] = __builtin_amdgcn_mfma_f32_16x16x32_f16(af[q], w1f[m][s], acc[m][q], 0, 0, 0);
        }

        // ---- h = relu(acc) * f -> h_lds (C/D: col=lane&15, row=(lane>>4)*4+reg)
#pragma unroll
        for (int m = 0; m < 2; ++m) {
            const int ch = chBase + m * 16 + l15;
#pragma unroll
            for (int q = 0; q < 4; ++q)
#pragma unroll
                for (int r = 0; r < 4; ++r) {
                    const int p = q * 16 + lg * 4 + r;
                    const int byte = (p * 256 + ch * 2) ^ ((p & 7) << 4);
                    const float fval = (float)*reinterpret_cast<const f16*>(
                        reinterpret_cast<const char*>(f_lds) + byte);
                    const float hv = fmaxf(acc[m][q][r], 0.f) * fval;
                    *reinterpret_cast<f16*>(reinterpret_cast<char*>(h_lds) + byte) = (f16)hv;
                }
        }
        __syncthreads();

        // ---- Layer 2: out = relu(h @ W2 + b2), scatter-store -------------
        f32x4 acc2[2][4];
#pragma unroll
        for (int m = 0; m < 2; ++m)
#pragma unroll
            for (int q = 0; q < 4; ++q)
                acc2[m][q] = (f32x4){b2v[m], b2v[m], b2v[m], b2v[m]};

#pragma unroll
        for (int s = 0; s < 4; ++s) {
            f16x8 af[4];
#pragma unroll
            for (int q = 0; q < 4; ++q) {
                const int p = q * 16 + l15;
                const int byte = (p * 256 + (s * 32 + lg * 8) * 2) ^ ((p & 7) << 4);
                U16 tmp;
                tmp.u = *reinterpret_cast<const uint4*>(reinterpret_cast<const char*>(h_lds) + byte);
                af[q] = tmp.h;
            }
#pragma unroll
            for (int m = 0; m < 2; ++m)
#pragma unroll
                for (int q = 0; q < 4; ++q)
                    acc2[m][q] = __builtin_amdgcn_mfma_f32_16x16x32_f16(af[q], w2f[m][s], acc2[m][q], 0, 0, 0);
        }

#pragma unroll
        for (int m = 0; m < 2; ++m) {
            const int ch = chBase + m * 16 + l15;
#pragma unroll
            for (int q = 0; q < 4; ++q)
#pragma unroll
                for (int r = 0; r < 4; ++r) {
                    const int slotIdx = q * 16 + lg * 4 + r;
                    if (tbase + slotIdx < eTot) {
                        const int p = pmap[slotIdx];
                        out[(size_t)p * C + ch] = fmaxf(acc2[m][q][r], 0.f);
                    }
                }
        }
        __syncthreads();  // protect os/f/h/pmap reuse next tile
    }
}

// -------------------------------------------------------------------------
// Launch
// -------------------------------------------------------------------------
extern "C" void kernel_launch(void* const* d_in, const int* in_sizes, int n_in,
                              void* d_out, int out_size, void* d_ws, size_t ws_size,
                              hipStream_t stream) {
    const float* feats = (const float*)d_in[0];
    const float* W1    = (const float*)d_in[1];
    const float* b1    = (const float*)d_in[2];
    const float* W2    = (const float*)d_in[3];
    const float* b2    = (const float*)d_in[4];
    const int*   idx   = (const int*)d_in[5];
    float*       out   = (float*)d_out;

    const int n = in_sizes[5];

    // Workspace: cnt[V] | off[V] | bsum[256] | csr[n]
    int* cnt  = (int*)d_ws;
    int* off  = cnt + V;
    int* bsum = off + V;
    int* csr  = bsum + 256;

    hipMemsetAsync(cnt, 0, (size_t)V * sizeof(int), stream);

    const int gridN = (n + 255) / 256;
    hist_kernel<<<gridN, 256, 0, stream>>>(idx, cnt, n);
    scan_block<<<V / 256, 256, 0, stream>>>(cnt, off, bsum);
    scan_bsum<<<1, 256, 0, stream>>>(bsum);
    add_bsum<<<V / 256, 256, 0, stream>>>(off, bsum);
    scatter_ids<<<gridN, 256, 0, stream>>>(idx, off, csr, n);

    fused_pool_mlp<<<V / VPB, BLOCK, 0, stream>>>(feats, W1, b1, W2, b2,
                                                  csr, off, out);
}